// Round 2
// baseline (1253.525 us; speedup 1.0000x reference)
//
#include <hip/hip_runtime.h>
#include <stdint.h>

typedef __bf16 bf16x8 __attribute__((ext_vector_type(8)));
typedef float f32x4 __attribute__((ext_vector_type(4)));
typedef unsigned short ushort_t;
typedef ushort_t ushort8 __attribute__((ext_vector_type(8)));

#define N_NODES 16384
#define D 128
#define BATCH 8192
#define NPOS 4096
#define NOUT 384

#define BM 128
#define BK 64
#define KSPLIT 16
#define KCHUNK (N_NODES / KSPLIT)   // 1024
#define NITER (KCHUNK / BK)         // 16

__device__ inline ushort_t f2bf_rhu(float f) {
    union { float f; uint32_t u; } v; v.f = f;
    return (ushort_t)((v.u + 0x8000u) >> 16);
}
// pack two f32 -> two bf16 in one u32 (round-half-up)
__device__ inline uint32_t pk2bf(float a, float b) {
    union { float f; uint32_t u; } x, y; x.f = a; y.f = b;
    return ((x.u + 0x8000u) >> 16) | ((y.u + 0x8000u) & 0xFFFF0000u);
}
union U8 { ushort8 v; uint32_t w[4]; };

__device__ inline ushort8 cvt2x4(const float4& p, const float4& q) {
    U8 t;
    t.w[0] = pk2bf(p.x, p.y);
    t.w[1] = pk2bf(p.z, p.w);
    t.w[2] = pk2bf(q.x, q.y);
    t.w[3] = pk2bf(q.z, q.w);
    return t.v;
}

// ---------------- E transpose + cvt: E[16384][128] f32 -> Et[128][16384] bf16 ----------------
__global__ __launch_bounds__(1024) void transpose_e(const float* __restrict__ E,
                                                    ushort_t* __restrict__ Et) {
    __shared__ float tile[32][33];
    int n0 = blockIdx.x * 32;   // over D
    int k0 = blockIdx.y * 32;   // over N_NODES
    int tx = threadIdx.x, ty = threadIdx.y;
    tile[ty][tx] = E[(size_t)(k0 + ty) * D + n0 + tx];
    __syncthreads();
    Et[(size_t)(n0 + ty) * N_NODES + k0 + tx] = f2bf_rhu(tile[tx][ty]);
}

// ---------------- index build + labels_out (f32) ----------------
__global__ void build_index(const int* __restrict__ labels, const int* __restrict__ nodeIdx,
                            int* __restrict__ rowNode, float* __restrict__ outLabels) {
    __shared__ int cnt[256], pfx[256];
    __shared__ int total;
    int t = threadIdx.x;
    int base = t * 32;
    int c = 0;
    for (int i = 0; i < 32; ++i) c += (labels[base + i] == 1);
    cnt[t] = c;
    __syncthreads();
    if (t == 0) {
        int run = 0;
        for (int j = 0; j < 256; ++j) { pfx[j] = run; run += cnt[j]; }
        total = run;
    }
    __syncthreads();
    int tp = total;
    int p = pfx[t];
    int q = base - p;
    for (int i = 0; i < 32; ++i) {
        int idx = base + i;
        int nd = nodeIdx[idx];
        if (labels[idx] == 1) { rowNode[p] = nd; ++p; }
        else                  { rowNode[tp + q] = nd; ++q; }
    }
    for (int i = t; i < BATCH; i += 256) outLabels[i] = (i < tp) ? 1.0f : 0.0f;
}

// ---------------- pos aggregation GEMM: xacc[4096][128] += Arows(f32->bf16) @ E ----------------
__global__ __launch_bounds__(256) void gemm_pos(const float* __restrict__ A,
                                                const ushort_t* __restrict__ Et,
                                                const int* __restrict__ rowNode,
                                                float* __restrict__ xacc) {
    __shared__ ushort_t As[BM][BK + 8];   // 128 x 72 bf16
    __shared__ ushort_t Bs[D][BK + 8];
    __shared__ int nid[BM];

    int t = threadIdx.x;
    int rb = blockIdx.x * BM;
    int kbase = blockIdx.y * KCHUNK;
    if (t < BM) nid[t] = rowNode[rb + t];
    __syncthreads();

    int wave = t >> 6;
    int lane = t & 63;
    int m = lane & 15;
    int qd = lane >> 4;

    f32x4 acc[2][8];
    for (int a = 0; a < 2; ++a)
        for (int c = 0; c < 8; ++c)
            acc[a][c] = (f32x4){0.f, 0.f, 0.f, 0.f};

    int srow = t >> 1;               // 0..127
    int skq  = (t & 1) * 32;         // 0 or 32

    float4 ar[8];
    ushort8 br[4];
    const size_t abase = (size_t)nid[srow] * N_NODES + kbase + skq;   // f32 elements
    const size_t bbase = (size_t)srow * N_NODES + kbase + skq;        // bf16 elements

    // prefetch kt = 0
    {
        const float4*  ap = (const float4*)(A + abase);
        const ushort8* bp = (const ushort8*)(Et + bbase);
        for (int i = 0; i < 8; ++i) ar[i] = ap[i];
        for (int i = 0; i < 4; ++i) br[i] = bp[i];
    }

    for (int kt = 0; kt < NITER; ++kt) {
        __syncthreads();
        {
            ushort8* as = (ushort8*)(&As[srow][skq]);
            ushort8* bs = (ushort8*)(&Bs[srow][skq]);
            for (int i = 0; i < 4; ++i) {
                as[i] = cvt2x4(ar[2 * i], ar[2 * i + 1]);
                bs[i] = br[i];
            }
        }
        __syncthreads();
        if (kt + 1 < NITER) {
            const float4*  ap = (const float4*)(A + abase + (size_t)(kt + 1) * BK);
            const ushort8* bp = (const ushort8*)(Et + bbase + (size_t)(kt + 1) * BK);
            for (int i = 0; i < 8; ++i) ar[i] = ap[i];
            for (int i = 0; i < 4; ++i) br[i] = bp[i];
        }
        for (int s = 0; s < 2; ++s) {
            int ko = s * 32 + qd * 8;
            bf16x8 af0 = *(const bf16x8*)(&As[wave * 32 + m][ko]);
            bf16x8 af1 = *(const bf16x8*)(&As[wave * 32 + 16 + m][ko]);
            for (int c = 0; c < 8; ++c) {
                bf16x8 bfv = *(const bf16x8*)(&Bs[c * 16 + m][ko]);
                acc[0][c] = __builtin_amdgcn_mfma_f32_16x16x32_bf16(af0, bfv, acc[0][c], 0, 0, 0);
                acc[1][c] = __builtin_amdgcn_mfma_f32_16x16x32_bf16(af1, bfv, acc[1][c], 0, 0, 0);
            }
        }
    }

    for (int a = 0; a < 2; ++a) {
        int row = rb + wave * 32 + a * 16 + qd * 4;
        for (int c = 0; c < 8; ++c) {
            int col = c * 16 + m;
            for (int j = 0; j < 4; ++j)
                atomicAdd(xacc + (size_t)(row + j) * D + col, acc[a][c][j]);
        }
    }
}

// ---------------- y GEMM: y[8192][384] = relu(x @ Wcat^T + b), f32 out ----------------
// x rows: mb<32 -> xacc (f32), mb>=32 -> gathered E rows (f32); all cvt to bf16 in staging.
__global__ __launch_bounds__(256) void gemm_y(const float* __restrict__ xacc,
                                              const float* __restrict__ E,
                                              const int* __restrict__ rowNode,
                                              const float* __restrict__ W,
                                              const float* __restrict__ bvec,
                                              float* __restrict__ outY) {
    __shared__ ushort_t Xs[BM][BK + 8];
    __shared__ ushort_t Ws[D][BK + 8];

    int t = threadIdx.x;
    int mb = blockIdx.x;    // 64 row blocks
    int nb = blockIdx.y;    // 3 col blocks (= layer)

    int wave = t >> 6;
    int lane = t & 63;
    int m = lane & 15;
    int qd = lane >> 4;

    f32x4 acc[2][8];
    for (int a = 0; a < 2; ++a)
        for (int c = 0; c < 8; ++c)
            acc[a][c] = (f32x4){0.f, 0.f, 0.f, 0.f};

    int srow = t >> 1;
    int skq  = (t & 1) * 32;

    int grow_s = mb * BM + srow;
    const float* xsrc;
    if (mb < 32) {
        xsrc = xacc + (size_t)grow_s * D + skq;
    } else {
        int nd = rowNode[grow_s];
        xsrc = E + (size_t)nd * D + skq;
    }
    const float* wsrc = W + ((size_t)nb * 128 + srow) * D + skq;

    for (int kt = 0; kt < 2; ++kt) {
        float4 xr[8], wr[8];
        const float4* xp = (const float4*)(xsrc + kt * BK);
        const float4* wp = (const float4*)(wsrc + kt * BK);
        for (int i = 0; i < 8; ++i) { xr[i] = xp[i]; wr[i] = wp[i]; }
        __syncthreads();
        {
            ushort8* xs = (ushort8*)(&Xs[srow][skq]);
            ushort8* ws = (ushort8*)(&Ws[srow][skq]);
            for (int i = 0; i < 4; ++i) {
                xs[i] = cvt2x4(xr[2 * i], xr[2 * i + 1]);
                ws[i] = cvt2x4(wr[2 * i], wr[2 * i + 1]);
            }
        }
        __syncthreads();
        for (int s = 0; s < 2; ++s) {
            int ko = s * 32 + qd * 8;
            bf16x8 af0 = *(const bf16x8*)(&Xs[wave * 32 + m][ko]);
            bf16x8 af1 = *(const bf16x8*)(&Xs[wave * 32 + 16 + m][ko]);
            for (int c = 0; c < 8; ++c) {
                bf16x8 bfv = *(const bf16x8*)(&Ws[c * 16 + m][ko]);
                acc[0][c] = __builtin_amdgcn_mfma_f32_16x16x32_bf16(af0, bfv, acc[0][c], 0, 0, 0);
                acc[1][c] = __builtin_amdgcn_mfma_f32_16x16x32_bf16(af1, bfv, acc[1][c], 0, 0, 0);
            }
        }
    }

    for (int a = 0; a < 2; ++a) {
        int rowloc = wave * 32 + a * 16 + qd * 4;
        int grow = mb * BM + rowloc;
        for (int c = 0; c < 8; ++c) {
            int col = c * 16 + m;
            int gcol = nb * 128 + col;
            float bias = bvec[gcol];
            for (int j = 0; j < 4; ++j) {
                float v = acc[a][c][j] + bias;
                v = v > 0.f ? v : 0.f;
                outY[(size_t)(grow + j) * NOUT + gcol] = v;
            }
        }
    }
}

extern "C" void kernel_launch(void* const* d_in, const int* in_sizes, int n_in,
                              void* d_out, int out_size, void* d_ws, size_t ws_size,
                              hipStream_t stream) {
    const int*   labels  = (const int*)d_in[0];
    const int*   nodeIdx = (const int*)d_in[1];
    const float* A       = (const float*)d_in[2];
    const float* E       = (const float*)d_in[3];
    const float* W       = (const float*)d_in[4];
    const float* b       = (const float*)d_in[5];
    float* out = (float*)d_out;

    char* ws = (char*)d_ws;
    ushort_t* Et      = (ushort_t*)(ws);                 // 128*16384*2 = 4 MiB
    float*    xacc    = (float*)(ws + (4u << 20));       // 4096*128*4  = 2 MiB
    int*      rowNode = (int*)(ws + (6u << 20));         // 32 KiB

    hipMemsetAsync(xacc, 0, (size_t)NPOS * D * sizeof(float), stream);
    transpose_e<<<dim3(D / 32, N_NODES / 32), dim3(32, 32), 0, stream>>>(E, Et);
    build_index<<<1, 256, 0, stream>>>(labels, nodeIdx, rowNode, out);
    gemm_pos<<<dim3(NPOS / BM, KSPLIT), 256, 0, stream>>>(A, Et, rowNode, xacc);
    gemm_y<<<dim3(BATCH / BM, 3), 256, 0, stream>>>(xacc, E, rowNode, W, b, out + BATCH);
}